// Round 1
// baseline (151.004 us; speedup 1.0000x reference)
//
#include <hip/hip_runtime.h>
#include <hip/hip_bf16.h>
#include <cstdint>
#include <cstddef>

#define BB   64
#define CINN 64
#define TS   4096
#define FF   128
#define KS   64
#define TOUT (TS - KS + 1)   // 4033

// ---- fused-kernel tiling ----
#define TSEG 256             // outputs per block (= one 256-output banded-MFMA tile)
#define XROW 320             // t-extent of staged x / computed y (TSEG + KS)
#define SXTW 35              // xT row stride in u32: 32 data cols + 3 pad (col 32/33 = sq->rinv)
#define YW   336             // yL cols: XROW + 16 finite-pad (zeroed; band coeffs there are 0)
#define YWW  (YW / 2)        // 168 u32 words per yL row (672 B, 16B-aligned rows)

typedef __attribute__((ext_vector_type(8))) short short8;
typedef __attribute__((ext_vector_type(4))) float f32x4;
union FragU { unsigned int u[4]; short8 v; uint4 q4; };

static __device__ __forceinline__ unsigned int f2bf_u(float f) {
    __hip_bfloat16 h = __float2bfloat16(f);
    return (unsigned int)*reinterpret_cast<unsigned short*>(&h);
}

// ---- Setup: banded temporal-B fragments (R5/R6-validated) + fused norm weights ----
// bandB[(f*3+s)*64 + lane] = 8 bf16: B_s[k=8q+j][n] = cw[32s+k-n] (0 outside [0,64))
__global__ void k_band(const float* __restrict__ cw, const float* __restrict__ sw,
                       const float* __restrict__ weight,
                       uint4* __restrict__ bandB, float* __restrict__ wnf) {
    const int f = blockIdx.x, l = threadIdx.x;
    const int n = l & 15, q = l >> 4;
    for (int s = 0; s < 3; ++s) {
        FragU o;
#pragma unroll
        for (int i = 0; i < 4; ++i) {
            int i0 = 32 * s + 8 * q + 2 * i - n;
            int i1 = i0 + 1;
            float a = (i0 >= 0 && i0 < KS) ? cw[(size_t)f * KS + i0] : 0.f;
            float c = (i1 >= 0 && i1 < KS) ? cw[(size_t)f * KS + i1] : 0.f;
            o.u[i] = f2bf_u(a) | (f2bf_u(c) << 16);
        }
        bandB[((size_t)f * 3 + s) * 64 + l] = o.q4;
    }
    // per-filter weight * rsqrt(|sw_f|^2 * |cw_f|^2) * scale / TOUT
    float a = sw[(size_t)f * CINN + l], c = cw[(size_t)f * KS + l];
    float v = a * a, u = c * c;
    for (int off = 32; off > 0; off >>= 1) {
        v += __shfl_down(v, off, 64);
        u += __shfl_down(u, off, 64);
    }
    if (l == 0) wnf[f] = weight[f] * rsqrtf(v * u) * (64.0f / (float)TOUT);
}

// ============ Fused kernel: x -> (spatial MFMA in LDS) -> banded temporal MFMA ============
// Block = (t-tile of 256 outputs) x (one batch). y NEVER touches HBM.
// LDS: xT 44,800 B (bf16 ch-pairs, pad-35 rows; pad cols 32/33 hold sq then rinv)
//      yL 86,016 B (128 filters x 336 bf16, rows 672 B -> 16B-aligned ds_read_b128)
__global__ __launch_bounds__(1024, 4) void k_fused(
    const float* __restrict__ x, const float* __restrict__ sw,
    const uint4* __restrict__ bandB, const float* __restrict__ wnf,
    const float* __restrict__ bias, float* __restrict__ out)
{
    __shared__ unsigned int xT[XROW * SXTW];   // 44,800 B
    __shared__ unsigned int yL[FF * YWW];      // 86,016 B (also reused as sq partials in phase 1)
    __shared__ float wred[16];

    const int tid = threadIdx.x;
    const int w = tid >> 6, l = tid & 63;
    const int b = blockIdx.y;
    const int t0 = blockIdx.x * TSEG;

    // ---------- Phase 1: stage xT (bf16 ch-pairs) + per-wave sq partials into yL scratch ----------
    {
        const float* xb = x + (size_t)b * CINN * TS;
        float* sqp = (float*)yL;               // [16][XROW] f32 partials
        float4 s4a = {0.f, 0.f, 0.f, 0.f}, s4b = {0.f, 0.f, 0.f, 0.f};
#pragma unroll
        for (int r = 0; r < 2; ++r) {
            const int cp = w + 16 * r;         // channel pair (2cp, 2cp+1)
            const float* x0 = xb + (size_t)(2 * cp) * TS;
            {
                int p = t0 + 4 * l; if (p > TS - 4) p = TS - 4;   // tail clamp (finite dup values)
                float4 v0 = *(const float4*)(x0 + p);
                float4 v1 = *(const float4*)(x0 + TS + p);
                s4a.x += v0.x * v0.x + v1.x * v1.x;
                s4a.y += v0.y * v0.y + v1.y * v1.y;
                s4a.z += v0.z * v0.z + v1.z * v1.z;
                s4a.w += v0.w * v0.w + v1.w * v1.w;
                const int t = 4 * l;
                xT[(t + 0) * SXTW + cp] = f2bf_u(v0.x) | (f2bf_u(v1.x) << 16);
                xT[(t + 1) * SXTW + cp] = f2bf_u(v0.y) | (f2bf_u(v1.y) << 16);
                xT[(t + 2) * SXTW + cp] = f2bf_u(v0.z) | (f2bf_u(v1.z) << 16);
                xT[(t + 3) * SXTW + cp] = f2bf_u(v0.w) | (f2bf_u(v1.w) << 16);
            }
            if (l < 16) {                      // t-local 256..319
                int p = t0 + 256 + 4 * l; if (p > TS - 4) p = TS - 4;
                float4 v0 = *(const float4*)(x0 + p);
                float4 v1 = *(const float4*)(x0 + TS + p);
                s4b.x += v0.x * v0.x + v1.x * v1.x;
                s4b.y += v0.y * v0.y + v1.y * v1.y;
                s4b.z += v0.z * v0.z + v1.z * v1.z;
                s4b.w += v0.w * v0.w + v1.w * v1.w;
                const int t = 256 + 4 * l;
                xT[(t + 0) * SXTW + cp] = f2bf_u(v0.x) | (f2bf_u(v1.x) << 16);
                xT[(t + 1) * SXTW + cp] = f2bf_u(v0.y) | (f2bf_u(v1.y) << 16);
                xT[(t + 2) * SXTW + cp] = f2bf_u(v0.z) | (f2bf_u(v1.z) << 16);
                xT[(t + 3) * SXTW + cp] = f2bf_u(v0.w) | (f2bf_u(v1.w) << 16);
            }
        }
        *(float4*)(sqp + w * XROW + 4 * l) = s4a;
        if (l < 16) *(float4*)(sqp + w * XROW + 256 + 4 * l) = s4b;
    }
    __syncthreads();

    // ---------- Phase 2: reduce sq partials (16 waves) into xT pad col 32 ----------
    if (tid < XROW) {
        const float* sqp = (const float*)yL;
        float s = 0.f;
#pragma unroll
        for (int w2 = 0; w2 < 16; ++w2) s += sqp[w2 * XROW + tid];
        xT[tid * SXTW + 32] = __float_as_uint(s);
    }
    __syncthreads();

    const int m = l & 15, q = l >> 4;

    // ---------- Phase 3a (wave 0 only): sliding-window rinv -> xT pad cols 32/33 ----------
    // Lockstep-safe: all window reads (program-order earlier) complete before any scatter store.
    if (w == 0 && l < 32) {
        const int base = 8 * l;
        float s = 0.f, hd[8], tl[8];
#pragma unroll
        for (int k = 0; k < 64; ++k) {
            float v = __uint_as_float(xT[(base + k) * SXTW + 32]);
            if (k < 8) hd[k] = v;
            s += v;
        }
#pragma unroll
        for (int j = 0; j < 8; ++j) tl[j] = __uint_as_float(xT[(base + 64 + j) * SXTW + 32]);
        float rv[8];
#pragma unroll
        for (int j = 0; j < 8; ++j) {
            int tpos = t0 + base + j;
            rv[j] = (tpos < TOUT) ? rsqrtf(s) : 0.f;   // masks tail outputs
            s += tl[j] - hd[j];
        }
#pragma unroll
        for (int j = 0; j < 8; ++j) {
            int t = base + j;
            xT[t * SXTW + 32 + ((t >> 6) & 1)] = __float_as_uint(rv[j]);
        }
    }

    // ---------- Phase 3b: spatial GEMM (A = sw bf16, B = xT) -> yL ----------
    {
        const int mw = w & 7, nh = w >> 3;     // M-tile (16 filters), n-half (10 tiles)
        short8 Af[2];
#pragma unroll
        for (int s = 0; s < 2; ++s) {
            const float* swr = sw + (size_t)(16 * mw + m) * CINN + s * 32 + q * 8;
            float4 w0 = *(const float4*)swr;
            float4 w1 = *(const float4*)(swr + 4);
            FragU fa;
            fa.u[0] = f2bf_u(w0.x) | (f2bf_u(w0.y) << 16);
            fa.u[1] = f2bf_u(w0.z) | (f2bf_u(w0.w) << 16);
            fa.u[2] = f2bf_u(w1.x) | (f2bf_u(w1.y) << 16);
            fa.u[3] = f2bf_u(w1.z) | (f2bf_u(w1.w) << 16);
            Af[s] = fa.v;
        }
        const bool evenl = (l & 1) == 0;
#pragma unroll
        for (int ti = 0; ti < 10; ++ti) {
            const int tt = nh * 10 + ti;
            const int t = tt * 16 + m;         // lane low-4 plays the n role
            const int bw = t * SXTW + 4 * q;
            FragU b0, b1;
#pragma unroll
            for (int i = 0; i < 4; ++i) { b0.u[i] = xT[bw + i]; b1.u[i] = xT[bw + 16 + i]; }
            f32x4 acc = {0.f, 0.f, 0.f, 0.f};
            acc = __builtin_amdgcn_mfma_f32_16x16x32_bf16(Af[0], b0.v, acc, 0, 0, 0);
            acc = __builtin_amdgcn_mfma_f32_16x16x32_bf16(Af[1], b1.v, acc, 0, 0, 0);
            // D: lane holds filters (16mw+4q+r) at t; pack n-parity pairs via shfl_xor
#pragma unroll
            for (int r = 0; r < 4; ++r) {
                float o = __shfl_xor(acc[r], 1, 64);
                if (evenl) {
                    unsigned u = f2bf_u(acc[r]) | (f2bf_u(o) << 16);
                    yL[(16 * mw + 4 * q + r) * YWW + 8 * tt + (m >> 1)] = u;
                }
            }
        }
        // zero the finite-pad cols 320..335 (multiplied by band zeros; must be finite)
        yL[(tid >> 3) * YWW + 160 + (tid & 7)] = 0u;
    }
    __syncthreads();

    // ---------- Phase 4: banded temporal MFMA, A-frags from yL (ds_read_b128) ----------
    float rr[4];
#pragma unroll
    for (int r = 0; r < 4; ++r) {
        int t = 64 * q + 16 * r + m;           // this lane's 4 output positions
        rr[r] = __uint_as_float(xT[t * SXTW + 32 + (q & 1)]);
    }
    const int f0t = 8 * w;
    float acc = 0.f;
    uint4 pb0, pb1, pb2;
    {
        const uint4* bb = bandB + (size_t)f0t * 3 * 64;
        pb0 = bb[l]; pb1 = bb[64 + l]; pb2 = bb[128 + l];
    }
#pragma unroll 2
    for (int fi = 0; fi < 8; ++fi) {
        const int f = f0t + fi;
        FragU B0, B1, B2;
        B0.q4 = pb0; B1.q4 = pb1; B2.q4 = pb2;
        if (fi < 7) {                          // prefetch next filter's band (L2)
            const uint4* bb = bandB + (size_t)(f + 1) * 3 * 64;
            pb0 = bb[l]; pb1 = bb[64 + l]; pb2 = bb[128 + l];
        }
        const int abase = f * YWW + 8 * m + 4 * q;   // 16B-aligned u32 word index
        FragU a0, a1, a2;
        a0.q4 = *(const uint4*)(yL + abase);
        a1.q4 = *(const uint4*)(yL + abase + 16);
        a2.q4 = *(const uint4*)(yL + abase + 32);
        f32x4 d = {0.f, 0.f, 0.f, 0.f};
        d = __builtin_amdgcn_mfma_f32_16x16x32_bf16(a0.v, B0.v, d, 0, 0, 0);
        d = __builtin_amdgcn_mfma_f32_16x16x32_bf16(a1.v, B1.v, d, 0, 0, 0);
        d = __builtin_amdgcn_mfma_f32_16x16x32_bf16(a2.v, B2.v, d, 0, 0, 0);
        float facc = 0.f;
#pragma unroll
        for (int r = 0; r < 4; ++r) facc += fabsf(d[r]) * rr[r];
        acc += wnf[f] * facc;
    }

    // ---------- block reduction + atomic ----------
    for (int off = 32; off > 0; off >>= 1) acc += __shfl_down(acc, off, 64);
    if (l == 0) wred[w] = acc;
    __syncthreads();
    if (tid == 0) {
        float s = 0.f;
#pragma unroll
        for (int i = 0; i < 16; ++i) s += wred[i];
        atomicAdd(out + b, s);
    }
    if (blockIdx.x == 0 && tid < FF) {
        float v = bias[tid];
        for (int off = 32; off > 0; off >>= 1) v += __shfl_down(v, off, 64);
        if ((tid & 63) == 0) atomicAdd(out + b, v);
    }
}

// --------- Fallback (no workspace): one block per (f,b), LDS rows ----------
__global__ __launch_bounds__(256) void k_naive(
    const float* __restrict__ x, const float* __restrict__ cw,
    const float* __restrict__ sw, const float* __restrict__ weight,
    const float* __restrict__ bias, float* __restrict__ out)
{
    __shared__ float yl[TS];
    __shared__ float ql[TS];
    __shared__ float wred[4];
    const int f = blockIdx.x, b = blockIdx.y, tid = threadIdx.x;
    for (int t = tid; t < TS; t += 256) {
        float a = 0.f, s = 0.f;
        for (int c = 0; c < CINN; ++c) {
            float v = x[((size_t)b * CINN + c) * TS + t];
            a += sw[(size_t)f * CINN + c] * v;
            s += v * v;
        }
        yl[t] = a; ql[t] = s;
    }
    __syncthreads();
    float acc = 0.f;
    for (int t = tid; t < TOUT; t += 256) {
        float cv = 0.f, sl = 0.f;
        for (int k = 0; k < KS; ++k) { cv += cw[(size_t)f * KS + k] * yl[t + k]; sl += ql[t + k]; }
        acc += fabsf(cv) * rsqrtf(sl);
    }
    float ssw = 0.f, scw = 0.f;
    for (int c = 0; c < CINN; ++c) { float v = sw[(size_t)f * CINN + c]; ssw += v * v; }
    for (int k = 0; k < KS; ++k)   { float v = cw[(size_t)f * KS + k];  scw += v * v; }
    const float wnf = weight[f] * rsqrtf(ssw * scw) * 64.0f / (float)TOUT;
    for (int off = 32; off > 0; off >>= 1) acc += __shfl_down(acc, off, 64);
    if ((tid & 63) == 0) wred[tid >> 6] = acc;
    __syncthreads();
    if (tid == 0) {
        float tot = (wred[0] + wred[1] + wred[2] + wred[3]) * wnf;
        if (f == 0) {
            float bsum = 0.f;
            for (int ff = 0; ff < FF; ++ff) bsum += bias[ff];
            tot += bsum;
        }
        atomicAdd(out + b, tot);
    }
}

extern "C" void kernel_launch(void* const* d_in, const int* in_sizes, int n_in,
                              void* d_out, int out_size, void* d_ws, size_t ws_size,
                              hipStream_t stream) {
    const float* x  = (const float*)d_in[0];
    const float* cw = (const float*)d_in[1];   // [F,K]
    const float* sw = (const float*)d_in[2];   // [F,CIN]
    const float* w  = (const float*)d_in[3];   // [F]
    const float* bs = (const float*)d_in[4];   // [F]
    float* out = (float*)d_out;

    hipMemsetAsync(d_out, 0, (size_t)out_size * sizeof(float), stream);

    const size_t bandBytes = (size_t)FF * 3 * 64 * 16;   // 384 KB
    const size_t wnBytes   = (size_t)FF * sizeof(float);

    if (bandBytes + wnBytes <= ws_size) {
        uint4* bandB = (uint4*)d_ws;
        float* wnf   = (float*)((char*)d_ws + bandBytes);
        k_band <<<dim3(FF), 64, 0, stream>>>(cw, sw, w, bandB, wnf);
        k_fused<<<dim3(TS / TSEG, BB), 1024, 0, stream>>>(x, sw, bandB, wnf, bs, out);
    } else {
        k_naive<<<dim3(FF, BB), 256, 0, stream>>>(x, cw, sw, w, bs, out);
    }
}